// Round 1
// baseline (3079.495 us; speedup 1.0000x reference)
//
#include <hip/hip_runtime.h>
#include <math.h>

// ---------------------------------------------------------------------------
// ChebConv GNN, fp32. N=100000 nodes, E=1600000 edges, D=64, K=5, 3 residuals.
// Pipeline per launch:
//   1. deg (atomic, by src) + in-degree count (by tgt)
//   2. dis = rsqrt(deg) in place
//   3. 3-kernel exclusive scan -> CSR rowptr/cursor
//   4. CSR fill (atomic cursor): csr_src, csr_w = -ea*dis[src]*dis[tgt]
//   5. encoder MLP (4->64->64, gelu x2)
//   6. 3x { 4 props + fused 5(6)-buffer GEMM }   (Chebyshev recurrence fused)
//   7. decoder (64->1->1)
// ---------------------------------------------------------------------------

__device__ __forceinline__ float gelu_f(float v) {
  return 0.5f * v * (1.0f + erff(v * 0.70710678118654752440f));
}

__global__ __launch_bounds__(256) void k_deg_cnt(const int* __restrict__ src,
                                                 const int* __restrict__ tgt,
                                                 const float* __restrict__ ea,
                                                 float* __restrict__ deg,
                                                 int* __restrict__ cnt, int E) {
  int e = blockIdx.x * 256 + threadIdx.x;
  if (e < E) {
    atomicAdd(&deg[src[e]], ea[e]);
    atomicAdd(&cnt[tgt[e]], 1);
  }
}

__global__ __launch_bounds__(256) void k_dis(float* __restrict__ deg, int n) {
  int i = blockIdx.x * 256 + threadIdx.x;
  if (i < n) {
    float d = deg[i];
    deg[i] = (d > 0.f) ? rsqrtf(d) : 0.f;
  }
}

// ---- scan: cnt[N] -> exclusive rowptr[N+1] (+ cursor copy) ----
__global__ __launch_bounds__(256) void k_scan1(const int* __restrict__ cnt,
                                               int* __restrict__ bsum, int n) {
  __shared__ int sd[256];
  int i = blockIdx.x * 256 + threadIdx.x;
  int v = (i < n) ? cnt[i] : 0;
  sd[threadIdx.x] = v;
  __syncthreads();
  for (int s = 128; s > 0; s >>= 1) {
    if (threadIdx.x < s) sd[threadIdx.x] += sd[threadIdx.x + s];
    __syncthreads();
  }
  if (threadIdx.x == 0) bsum[blockIdx.x] = sd[0];
}

__global__ __launch_bounds__(1024) void k_scan2(int* __restrict__ bsum, int nb) {
  // one block of 1024 threads; nb <= 1024
  __shared__ int sd[1024];
  int t = threadIdx.x;
  int v = (t < nb) ? bsum[t] : 0;
  sd[t] = v;
  __syncthreads();
  for (int off = 1; off < 1024; off <<= 1) {
    int x = (t >= off) ? sd[t - off] : 0;
    __syncthreads();
    sd[t] += x;
    __syncthreads();
  }
  if (t < nb) bsum[t] = sd[t] - v;  // exclusive
}

__global__ __launch_bounds__(256) void k_scan3(const int* __restrict__ cnt,
                                               const int* __restrict__ bsum,
                                               int* __restrict__ rowptr,
                                               int* __restrict__ cursor, int n,
                                               int Etot) {
  __shared__ int sd[256];
  int t = threadIdx.x;
  int i = blockIdx.x * 256 + t;
  int v = (i < n) ? cnt[i] : 0;
  sd[t] = v;
  __syncthreads();
  for (int off = 1; off < 256; off <<= 1) {
    int x = (t >= off) ? sd[t - off] : 0;
    __syncthreads();
    sd[t] += x;
    __syncthreads();
  }
  int excl = bsum[blockIdx.x] + sd[t] - v;
  if (i < n) {
    rowptr[i] = excl;
    cursor[i] = excl;
  }
  if (i == n) rowptr[n] = Etot;
}

__global__ __launch_bounds__(256) void k_fill(const int* __restrict__ src,
                                              const int* __restrict__ tgt,
                                              const float* __restrict__ ea,
                                              const float* __restrict__ dis,
                                              int* __restrict__ cursor,
                                              int* __restrict__ csrc,
                                              float* __restrict__ cw, int E) {
  int e = blockIdx.x * 256 + threadIdx.x;
  if (e < E) {
    int s = src[e], t = tgt[e];
    int pos = atomicAdd(&cursor[t], 1);
    csrc[pos] = s;
    cw[pos] = -ea[e] * dis[s] * dis[t];
  }
}

// ---- encoder: h = gelu(gelu(x@w1+b1)@w2+b2), x is (N,4) ----
__global__ __launch_bounds__(256) void k_encode(
    const float* __restrict__ x, const float* __restrict__ w1,
    const float* __restrict__ b1, const float* __restrict__ w2,
    const float* __restrict__ b2, float* __restrict__ h, int n) {
  __shared__ float sw1[4 * 64];
  __shared__ float sb1[64];
  __shared__ float sw2[64 * 64];
  __shared__ float sb2[64];
  __shared__ float smid[4][64];
  if (threadIdx.x < 256) sw1[threadIdx.x] = w1[threadIdx.x];
  if (threadIdx.x < 64) {
    sb1[threadIdx.x] = b1[threadIdx.x];
    sb2[threadIdx.x] = b2[threadIdx.x];
  }
  for (int i = threadIdx.x; i < 4096; i += 256) sw2[i] = w2[i];
  __syncthreads();
  const int wave = threadIdx.x >> 6;
  const int lane = threadIdx.x & 63;
  for (int base = blockIdx.x * 4; base < n; base += gridDim.x * 4) {
    const int node = base + wave;
    const bool ok = node < n;
    float m = 0.f;
    if (ok) {
      const float4 xv = *(const float4*)(x + (size_t)node * 4);
      m = xv.x * sw1[lane] + xv.y * sw1[64 + lane] + xv.z * sw1[128 + lane] +
          xv.w * sw1[192 + lane] + sb1[lane];
      m = gelu_f(m);
    }
    smid[wave][lane] = m;
    __syncthreads();
    float o = sb2[lane];
#pragma unroll 8
    for (int k = 0; k < 64; ++k) o += smid[wave][k] * sw2[k * 64 + lane];
    if (ok) h[(size_t)node * 64 + lane] = gelu_f(o);
    __syncthreads();
  }
}

// ---- prop: out = alpha*segsum - prev   (wave per node, lane = channel) ----
template <bool HASPREV>
__global__ __launch_bounds__(256) void k_prop(
    const float* __restrict__ hin, const int* __restrict__ rowptr,
    const int* __restrict__ csrc, const float* __restrict__ cw,
    const float* __restrict__ prev, float* __restrict__ out, int n) {
  const int gw = (blockIdx.x * 256 + threadIdx.x) >> 6;  // node
  const int lane = threadIdx.x & 63;
  if (gw >= n) return;
  const int beg = rowptr[gw];
  const int end = rowptr[gw + 1];
  float acc = 0.f;
  int j = beg;
  for (; j + 1 < end; j += 2) {
    int s0 = csrc[j], s1 = csrc[j + 1];
    float w0 = cw[j], w1 = cw[j + 1];
    acc += w0 * hin[(size_t)s0 * 64 + lane];
    acc += w1 * hin[(size_t)s1 * 64 + lane];
  }
  if (j < end) acc += cw[j] * hin[(size_t)csrc[j] * 64 + lane];
  float r;
  if (HASPREV)
    r = 2.f * acc - prev[(size_t)gw * 64 + lane];
  else
    r = acc;
  out[(size_t)gw * 64 + lane] = r;
}

// ---- fused multi-buffer GEMM: out = maybe_gelu(sum_k A_k @ W_k + biases) ----
// A_0 = A0; A_k = Atx + (k-1)*N*64 for k=1..NB-1; optional extra (Aex, Wex).
// 256 threads, 64-row tile, 4x4 register tile per thread.
template <int NB, bool HASEX, bool GELU>
__global__ __launch_bounds__(256) void k_gemm_multi(
    const float* __restrict__ A0, const float* __restrict__ Atx,
    const float* __restrict__ Wb, const float* __restrict__ Aex,
    const float* __restrict__ Wex, const float* __restrict__ bias1,
    const float* __restrict__ bias2, float* __restrict__ out, int n) {
  __shared__ float sA[64 * 68];  // transposed [k][row], stride 68 (aligned, 2-way)
  __shared__ float sW[64 * 64];  // row-major [k][col]
  const int tid = threadIdx.x;
  const int rbase = blockIdx.x * 64;
  const int c4 = (tid & 15) * 4;
  const int rg = tid >> 4;  // 0..15
  const int r4 = rg * 4;
  const size_t n64 = (size_t)n * 64;

  float acc[4][4];
#pragma unroll
  for (int i = 0; i < 4; ++i)
#pragma unroll
    for (int j = 0; j < 4; ++j) acc[i][j] = 0.f;

  const int total = NB + (HASEX ? 1 : 0);
  for (int kb = 0; kb < total; ++kb) {
    const float* Ap =
        (kb == 0) ? A0 : (kb < NB ? Atx + (size_t)(kb - 1) * n64 : Aex);
    const float* Wp = (kb < NB) ? Wb + kb * 4096 : Wex;
    __syncthreads();
#pragma unroll
    for (int i = 0; i < 4; ++i) {
      const int row = rg + 16 * i;
      const int grow = rbase + row;
      float4 v = make_float4(0.f, 0.f, 0.f, 0.f);
      if (grow < n) v = *(const float4*)(Ap + (size_t)grow * 64 + c4);
      sA[(c4 + 0) * 68 + row] = v.x;
      sA[(c4 + 1) * 68 + row] = v.y;
      sA[(c4 + 2) * 68 + row] = v.z;
      sA[(c4 + 3) * 68 + row] = v.w;
      *(float4*)(sW + row * 64 + c4) = *(const float4*)(Wp + row * 64 + c4);
    }
    __syncthreads();
#pragma unroll 8
    for (int kk = 0; kk < 64; ++kk) {
      const float4 a = *(const float4*)(sA + kk * 68 + r4);
      const float4 w = *(const float4*)(sW + kk * 64 + c4);
      acc[0][0] += a.x * w.x; acc[0][1] += a.x * w.y;
      acc[0][2] += a.x * w.z; acc[0][3] += a.x * w.w;
      acc[1][0] += a.y * w.x; acc[1][1] += a.y * w.y;
      acc[1][2] += a.y * w.z; acc[1][3] += a.y * w.w;
      acc[2][0] += a.z * w.x; acc[2][1] += a.z * w.y;
      acc[2][2] += a.z * w.z; acc[2][3] += a.z * w.w;
      acc[3][0] += a.w * w.x; acc[3][1] += a.w * w.y;
      acc[3][2] += a.w * w.z; acc[3][3] += a.w * w.w;
    }
  }
  float bb[4];
#pragma unroll
  for (int j = 0; j < 4; ++j) {
    float b = bias1 ? bias1[c4 + j] : 0.f;
    if (bias2) b += bias2[c4 + j];
    bb[j] = b;
  }
#pragma unroll
  for (int i = 0; i < 4; ++i) {
    const int grow = rbase + r4 + i;
    if (grow < n) {
      float v0 = acc[i][0] + bb[0];
      float v1 = acc[i][1] + bb[1];
      float v2 = acc[i][2] + bb[2];
      float v3 = acc[i][3] + bb[3];
      if (GELU) {
        v0 = gelu_f(v0); v1 = gelu_f(v1);
        v2 = gelu_f(v2); v3 = gelu_f(v3);
      }
      float4 o; o.x = v0; o.y = v1; o.z = v2; o.w = v3;
      *(float4*)(out + (size_t)grow * 64 + c4) = o;
    }
  }
}

// ---- decoder: out[n] = gelu(dot(h[n], d1w) + d1b)*d2w + d2b ----
__global__ __launch_bounds__(256) void k_decode(
    const float* __restrict__ h, const float* __restrict__ d1w,
    const float* __restrict__ d1b, const float* __restrict__ d2w,
    const float* __restrict__ d2b, float* __restrict__ out, int n) {
  const int q = (blockIdx.x * 256 + threadIdx.x) >> 4;  // node
  const int l = threadIdx.x & 15;
  if (q >= n) return;
  const float4 v = *(const float4*)(h + (size_t)q * 64 + l * 4);
  const float4 w = *(const float4*)(d1w + l * 4);
  float s = v.x * w.x + v.y * w.y + v.z * w.z + v.w * w.w;
  s += __shfl_xor(s, 1, 64);
  s += __shfl_xor(s, 2, 64);
  s += __shfl_xor(s, 4, 64);
  s += __shfl_xor(s, 8, 64);
  if (l == 0) out[q] = gelu_f(s + d1b[0]) * d2w[0] + d2b[0];
}

extern "C" void kernel_launch(void* const* d_in, const int* in_sizes, int n_in,
                              void* d_out, int out_size, void* d_ws,
                              size_t ws_size, hipStream_t stream) {
  const float* x = (const float*)d_in[0];
  const int* ei = (const int*)d_in[1];
  const float* ea = (const float*)d_in[2];
  const float* e1w = (const float*)d_in[3];
  const float* e1b = (const float*)d_in[4];
  const float* e2w = (const float*)d_in[5];
  const float* e2b = (const float*)d_in[6];
  const float* cw1 = (const float*)d_in[7];
  const float* cb1 = (const float*)d_in[8];
  const float* cw2 = (const float*)d_in[9];
  const float* cb2 = (const float*)d_in[10];
  const float* lw = (const float*)d_in[11];
  const float* lb = (const float*)d_in[12];
  const float* d1w = (const float*)d_in[13];
  const float* d1b = (const float*)d_in[14];
  const float* d2w = (const float*)d_in[15];
  const float* d2b = (const float*)d_in[16];

  const int N = in_sizes[0] / 4;
  const int E = in_sizes[2];
  const int* src = ei;
  const int* tgt = ei + E;

  char* p = (char*)d_ws;
  auto carve = [&](size_t bytes) -> char* {
    char* r = p;
    p += (bytes + 255) & ~(size_t)255;
    return r;
  };
  float* deg = (float*)carve((size_t)N * 4);       // becomes dis in place
  int* cnt = (int*)carve((size_t)N * 4);
  int* rowptr = (int*)carve((size_t)(N + 1) * 4);
  int* cursor = (int*)carve((size_t)N * 4);
  int* bsum = (int*)carve(1024 * 4);
  int* csrc = (int*)carve((size_t)E * 4);
  float* cwn = (float*)carve((size_t)E * 4);
  float* h = (float*)carve((size_t)N * 64 * 4);
  float* t = (float*)carve((size_t)N * 64 * 4);
  float* Tx = (float*)carve((size_t)4 * N * 64 * 4);
  (void)ws_size;

  hipMemsetAsync(deg, 0, (size_t)N * 4, stream);
  hipMemsetAsync(cnt, 0, (size_t)N * 4, stream);

  const int gE = (E + 255) / 256;
  const int gN = (N + 255) / 256;
  const int gS = (N + 1 + 255) / 256;  // covers i == N for rowptr[N]
  k_deg_cnt<<<gE, 256, 0, stream>>>(src, tgt, ea, deg, cnt, E);
  k_dis<<<gN, 256, 0, stream>>>(deg, N);
  k_scan1<<<gS, 256, 0, stream>>>(cnt, bsum, N);
  k_scan2<<<1, 1024, 0, stream>>>(bsum, gS);
  k_scan3<<<gS, 256, 0, stream>>>(cnt, bsum, rowptr, cursor, N, E);
  k_fill<<<gE, 256, 0, stream>>>(src, tgt, ea, deg, cursor, csrc, cwn, E);
  k_encode<<<2048, 256, 0, stream>>>(x, e1w, e1b, e2w, e2b, h, N);

  const size_t n64 = (size_t)N * 64;
  const int gP = (int)((n64 + 255) / 256);
  const int gG = (N + 63) / 64;
  for (int b = 0; b < 3; ++b) {
    const float* cw1b = cw1 + (size_t)b * 5 * 4096;
    const float* cb1b = cb1 + b * 64;
    const float* cw2b = cw2 + (size_t)b * 5 * 4096;
    const float* cb2b = cb2 + b * 64;
    const float* lwb = lw + (size_t)b * 4096;
    const float* lbb = lb + b * 64;
    float* Tx1 = Tx;
    float* Tx2 = Tx + n64;
    float* Tx3 = Tx + 2 * n64;
    float* Tx4 = Tx + 3 * n64;

    // conv1: t = gelu(sum_k Tx_k @ w1_k + cb1)
    k_prop<false><<<gP, 256, 0, stream>>>(h, rowptr, csrc, cwn, nullptr, Tx1, N);
    k_prop<true><<<gP, 256, 0, stream>>>(Tx1, rowptr, csrc, cwn, h, Tx2, N);
    k_prop<true><<<gP, 256, 0, stream>>>(Tx2, rowptr, csrc, cwn, Tx1, Tx3, N);
    k_prop<true><<<gP, 256, 0, stream>>>(Tx3, rowptr, csrc, cwn, Tx2, Tx4, N);
    k_gemm_multi<5, false, true><<<gG, 256, 0, stream>>>(
        h, Tx, cw1b, nullptr, nullptr, cb1b, nullptr, t, N);

    // conv2 + residual: h = gelu(sum_k Ty_k @ w2_k + cb2 + h@lw + lb)
    k_prop<false><<<gP, 256, 0, stream>>>(t, rowptr, csrc, cwn, nullptr, Tx1, N);
    k_prop<true><<<gP, 256, 0, stream>>>(Tx1, rowptr, csrc, cwn, t, Tx2, N);
    k_prop<true><<<gP, 256, 0, stream>>>(Tx2, rowptr, csrc, cwn, Tx1, Tx3, N);
    k_prop<true><<<gP, 256, 0, stream>>>(Tx3, rowptr, csrc, cwn, Tx2, Tx4, N);
    k_gemm_multi<5, true, true><<<gG, 256, 0, stream>>>(
        t, Tx, cw2b, h, lwb, cb2b, lbb, h, N);
  }

  const int gD = (int)(((size_t)N * 16 + 255) / 256);
  k_decode<<<gD, 256, 0, stream>>>(h, d1w, d1b, d2w, d2b, (float*)d_out, N);
}